// Round 7
// baseline (227.201 us; speedup 1.0000x reference)
//
#include <hip/hip_runtime.h>
#include <hip/hip_bf16.h>
#include <cstdint>
#include <cstddef>

// ---------------------------------------------------------------------------
// MultiHeadAttention  B=2 S=2048 E=1024 H=16 D=64 causal, bf16 MFMA path.
// k_prep -> qkv gemm (ring-3 BK=32) -> flash attn (32x32 MFMA, 32 q-rows/wave,
// ring-4, raw barrier + vmcnt(8)) -> out gemm (ring-3 BK=32).
// ---------------------------------------------------------------------------

typedef unsigned short u16;
typedef __attribute__((ext_vector_type(8))) short short8;
typedef __attribute__((ext_vector_type(4))) float floatx4;
typedef __attribute__((ext_vector_type(16))) float floatx16;

#define MFMA16(a, b, c) __builtin_amdgcn_mfma_f32_16x16x32_bf16((a), (b), (c), 0, 0, 0)
#define MFMA32(a, b, c) __builtin_amdgcn_mfma_f32_32x32x16_bf16((a), (b), (c), 0, 0, 0)

#if __has_builtin(__builtin_amdgcn_exp2f)
#define EXP2(x) __builtin_amdgcn_exp2f(x)
#else
#define EXP2(x) exp2f(x)
#endif

#define QSCALE 0.18033688011f  // 0.125 * log2(e)
#define NEGINF (-__builtin_inff())

static __device__ __forceinline__ u16 f2b(float f) {
    union { float f; uint32_t u; } v; v.f = f;
    return (u16)((v.u + 0x7fffu + ((v.u >> 16) & 1u)) >> 16);  // RNE
}

static __device__ __forceinline__ uint32_t pkbf(float lo, float hi) {
    union { float f; uint32_t u; } a, b; a.f = lo; b.f = hi;
    return __builtin_amdgcn_perm(b.u + 0x8000u, a.u + 0x8000u, 0x07060302u);
}

static __device__ __forceinline__ void async_cp16(const u16* g, u16* lds_wave_base) {
    __builtin_amdgcn_global_load_lds((__attribute__((address_space(1))) void*)g,
                                     (__attribute__((address_space(3))) void*)lds_wave_base,
                                     16, 0, 0);
}

// ---------------- fused prep: x->bf16, W_qkv^T->bf16, W_out^T->bf16 ---------

__global__ __launch_bounds__(256) void k_prep(const float* __restrict__ x,
                                              const float* __restrict__ Wq,
                                              const float* __restrict__ Wo,
                                              u16* __restrict__ xb,
                                              u16* __restrict__ wqkvT,
                                              u16* __restrict__ woutT) {
    int bx = blockIdx.x, tid = threadIdx.x;
    if (bx < 2048) {
        int g = bx * 256 + tid;
        const float4* s = (const float4*)x + (size_t)g * 2;
        float4 f0 = s[0], f1 = s[1];
        uint4 r;
        r.x = pkbf(f0.x, f0.y);
        r.y = pkbf(f0.z, f0.w);
        r.z = pkbf(f1.x, f1.y);
        r.w = pkbf(f1.z, f1.w);
        *(uint4*)(xb + (size_t)g * 8) = r;
        return;
    }
    __shared__ float t[32][33];
    const float* src;
    u16* dst;
    int R, C, b;
    if (bx < 5120) { b = bx - 2048; src = Wq; dst = wqkvT; R = 1024; C = 3072; }
    else           { b = bx - 5120; src = Wo; dst = woutT; R = 1024; C = 1024; }
    int nbx = C >> 5;
    int yq = b / nbx, xq = b - yq * nbx;
    int c0 = xq * 32, r0 = yq * 32;
    int tx = tid & 31, ty = tid >> 5;
#pragma unroll
    for (int i = 0; i < 4; ++i)
        t[ty + i * 8][tx] = src[(size_t)(r0 + ty + i * 8) * C + c0 + tx];
    __syncthreads();
#pragma unroll
    for (int i = 0; i < 4; ++i)
        dst[(size_t)(c0 + ty + i * 8) * R + r0 + tx] = f2b(t[tx][ty + i * 8]);
}

// ---------------- qkv GEMM: 128x128, BK=32, ring-3 pipeline -----------------

__global__ __launch_bounds__(256, 3) void k_qkv_gemm(const u16* __restrict__ A,
                                                     const u16* __restrict__ Bt,
                                                     const float* __restrict__ bias,
                                                     u16* __restrict__ Qb,
                                                     u16* __restrict__ Kb,
                                                     u16* __restrict__ Vtb) {
    __shared__ __align__(16) u16 As[3][128 * 32];
    __shared__ __align__(16) u16 Bs[3][128 * 32];
    int tid = threadIdx.x;
    int w = tid >> 6, lane = tid & 63, quad = lane >> 4, l16 = lane & 15;
    int wm = w >> 1, wn = w & 1;
    int m0 = blockIdx.y * 128, n0 = blockIdx.x * 128;
    int wb = (tid & ~63) * 8;

    int ra0 = tid >> 2, ca0 = (tid & 3) * 8;
    int ra1 = (256 + tid) >> 2, ca1 = (tid & 3) * 8;
    const u16* A0 = &A[(size_t)(m0 + ra0) * 1024 + ca0];
    const u16* A1 = &A[(size_t)(m0 + ra1) * 1024 + ca1];
    const u16* B0 = &Bt[(size_t)(n0 + ra0) * 1024 + ca0];
    const u16* B1 = &Bt[(size_t)(n0 + ra1) * 1024 + ca1];

    auto stage = [&](int src_kt, int slot) {
        int ko = src_kt * 32;
        async_cp16(A0 + ko, &As[slot][wb]);
        async_cp16(A1 + ko, &As[slot][2048 + wb]);
        async_cp16(B0 + ko, &Bs[slot][wb]);
        async_cp16(B1 + ko, &Bs[slot][2048 + wb]);
    };

    floatx4 acc[4][4] = {};
    stage(0, 0);
    stage(1, 1);

    for (int kt = 0; kt < 32; ++kt) {
        asm volatile("s_waitcnt vmcnt(4)" ::: "memory");
        asm volatile("s_barrier" ::: "memory");
        int jn = kt + 2;
        stage(jn < 32 ? jn : 31, jn % 3);
        int s = kt % 3;
        short8 af[4], bf[4];
#pragma unroll
        for (int mt = 0; mt < 4; ++mt)
            af[mt] = *(const short8*)&As[s][(wm * 64 + mt * 16 + l16) * 32 + quad * 8];
#pragma unroll
        for (int nt = 0; nt < 4; ++nt)
            bf[nt] = *(const short8*)&Bs[s][(wn * 64 + nt * 16 + l16) * 32 + quad * 8];
#pragma unroll
        for (int mt = 0; mt < 4; ++mt)
#pragma unroll
            for (int nt = 0; nt < 4; ++nt)
                acc[mt][nt] = MFMA16(af[mt], bf[nt], acc[mt][nt]);
    }

    int region = n0 >> 10;  // 0=Q 1=K 2=V
    if (region == 2) {
#pragma unroll
        for (int mt = 0; mt < 4; ++mt)
#pragma unroll
            for (int nt = 0; nt < 4; ++nt) {
                int n_abs = n0 + wn * 64 + nt * 16 + l16;
                int e = n_abs & 1023, h = e >> 6, d = e & 63;
                float vb = bias[n_abs];
                int mrow = m0 + wm * 64 + mt * 16 + quad * 4;
                int b = mrow >> 11, s0 = mrow & 2047;
                uint2 val;
                val.x = pkbf(acc[mt][nt][0] + vb, acc[mt][nt][1] + vb);
                val.y = pkbf(acc[mt][nt][2] + vb, acc[mt][nt][3] + vb);
                *(uint2*)&Vtb[((size_t)(b * 16 + h) * 64 + d) * 2048 + s0] = val;
            }
    } else {
        u16* dst = region == 0 ? Qb : Kb;
        float scl = region == 0 ? QSCALE : 1.0f;
#pragma unroll
        for (int mt = 0; mt < 4; ++mt)
#pragma unroll
            for (int nt = 0; nt < 4; ++nt)
#pragma unroll
                for (int r = 0; r < 4; ++r) {
                    int m_abs = m0 + wm * 64 + mt * 16 + quad * 4 + r;
                    int n_abs = n0 + wn * 64 + nt * 16 + l16;
                    float val = (acc[mt][nt][r] + bias[n_abs]) * scl;
                    int e = n_abs & 1023, h = e >> 6, d = e & 63;
                    int b = m_abs >> 11, s = m_abs & 2047;
                    dst[((size_t)(b * 16 + h) * 2048 + s) * 64 + d] = f2b(val);
                }
    }
}

// ---------------- out GEMM: 64x128, BK=32, ring-3 pipeline ------------------

__global__ __launch_bounds__(256, 4) void k_out_gemm(const u16* __restrict__ A,
                                                     const u16* __restrict__ Bt,
                                                     const float* __restrict__ bias,
                                                     float* __restrict__ out) {
    __shared__ __align__(16) u16 As[3][64 * 32];
    __shared__ __align__(16) u16 Bs[3][128 * 32];
    int tid = threadIdx.x;
    int w = tid >> 6, lane = tid & 63, quad = lane >> 4, l16 = lane & 15;
    int wm = w >> 1, wn = w & 1;
    int m0 = blockIdx.y * 64, n0 = blockIdx.x * 128;
    int wb = (tid & ~63) * 8;

    int ra0 = tid >> 2, ca0 = (tid & 3) * 8;
    int ra1 = (256 + tid) >> 2;
    const u16* A0 = &A[(size_t)(m0 + ra0) * 1024 + ca0];
    const u16* B0 = &Bt[(size_t)(n0 + ra0) * 1024 + ca0];
    const u16* B1 = &Bt[(size_t)(n0 + ra1) * 1024 + ca0];

    auto stage = [&](int src_kt, int slot) {
        int ko = src_kt * 32;
        async_cp16(A0 + ko, &As[slot][wb]);
        async_cp16(B0 + ko, &Bs[slot][wb]);
        async_cp16(B1 + ko, &Bs[slot][2048 + wb]);
    };

    floatx4 acc[2][4] = {};
    stage(0, 0);
    stage(1, 1);

    for (int kt = 0; kt < 32; ++kt) {
        asm volatile("s_waitcnt vmcnt(3)" ::: "memory");
        asm volatile("s_barrier" ::: "memory");
        int jn = kt + 2;
        stage(jn < 32 ? jn : 31, jn % 3);
        int s = kt % 3;
        short8 af[2], bf[4];
#pragma unroll
        for (int mt = 0; mt < 2; ++mt)
            af[mt] = *(const short8*)&As[s][(wm * 32 + mt * 16 + l16) * 32 + quad * 8];
#pragma unroll
        for (int nt = 0; nt < 4; ++nt)
            bf[nt] = *(const short8*)&Bs[s][(wn * 64 + nt * 16 + l16) * 32 + quad * 8];
#pragma unroll
        for (int mt = 0; mt < 2; ++mt)
#pragma unroll
            for (int nt = 0; nt < 4; ++nt)
                acc[mt][nt] = MFMA16(af[mt], bf[nt], acc[mt][nt]);
    }

#pragma unroll
    for (int mt = 0; mt < 2; ++mt)
#pragma unroll
        for (int nt = 0; nt < 4; ++nt)
#pragma unroll
            for (int r = 0; r < 4; ++r) {
                int m_abs = m0 + wm * 32 + mt * 16 + quad * 4 + r;
                int n_abs = n0 + wn * 64 + nt * 16 + l16;
                out[(size_t)m_abs * 1024 + n_abs] = acc[mt][nt][r] + bias[n_abs];
            }
}

// ---------------- flash attention: 32x32 MFMA, 32 q-rows per wave -----------
// grid 512: bh = (L&7)*4 + (L>>3)&3 (heads L2-local per XCD). Merged pair
// (pr, 31-pr); 4 waves: 2 per tile, strip = 32 q-rows each; role flipped by
// (L>>8)&1 so each SIMD gets one B-wave (always active) + one A-wave.
// QK^T: S^T[key][q] via mfma_32x32x16 (A=K-frag from LDS, B=Q-frag regs);
// C-layout: q = lane&31 (lane-local stats!), key rows split across lane
// halves. PV: B-frag (P) needs keys 8-consecutive per half -> 2 shfl_xor(32)
// per 16-key block. A-frag (V^T) read b128 from LDS. Ring-4 + vmcnt(8).

__global__ __launch_bounds__(256, 2) void k_attn(const u16* __restrict__ Qb,
                                                 const u16* __restrict__ Kb,
                                                 const u16* __restrict__ Vtb,
                                                 u16* __restrict__ attnb) {
    __shared__ __align__(16) u16 KV[4][2][4096];  // [slot][K/V][64x64]
    int tid = threadIdx.x;
    int w = tid >> 6, lane = tid & 63;
    int l31 = lane & 31, h5 = lane >> 5;
    int L = blockIdx.x;
    int bh = ((L & 7) << 2) | ((L >> 3) & 3);
    int idx = (L >> 5) & 15;
    int pr = idx < 8 ? idx : 23 - idx;
    int qta = pr, qtb = 31 - pr;
    const u16* Qp = Qb + (size_t)bh * 131072;
    const u16* Kp = Kb + (size_t)bh * 131072;
    const u16* Vp = Vtb + (size_t)bh * 131072;
    int b = bh >> 4, h = bh & 15;

    int flip = (L >> 8) & 1;
    int roleA = ((w >> 1) ^ flip) & 1;  // 1 -> tile A (qta), 0 -> tile B (qtb)
    int strip = w & 1;
    int myqt = roleA ? qta : qtb;
    int q_abs = myqt * 64 + strip * 32 + l31;

    // staging offsets (XOR-swizzled chunk layout, wave-uniform LDS base)
    int r0 = tid >> 3, c0 = ((tid & 7) ^ (r0 & 7)) * 8;
    int f1 = 256 + tid;
    int r1 = f1 >> 3, c1 = ((f1 & 7) ^ (r1 & 7)) * 8;
    int kOff0 = r0 * 64 + c0, kOff1 = r1 * 64 + c1;
    int vOff0 = r0 * 2048 + c0, vOff1 = r1 * 2048 + c1;
    int wb = (tid & ~63) * 8;

    // Q B-frags (registers): qf[ck] holds Q[q_abs][ck*16 + h5*8 + j]
    short8 qf[4];
#pragma unroll
    for (int ck = 0; ck < 4; ++ck)
        qf[ck] = *(const short8*)&Qp[(size_t)q_abs * 64 + ck * 16 + h5 * 8];

    int n = qtb + 1;
    int my_n = myqt + 1;

    auto stage = [&](int j) {
        u16* Ks = (u16*)KV[j & 3][0];
        u16* Vs = (u16*)KV[j & 3][1];
        const u16* kp = Kp + (size_t)j * 4096;
        const u16* vp = Vp + (size_t)j * 64;
        async_cp16(kp + kOff0, Ks + wb);
        async_cp16(kp + kOff1, Ks + 2048 + wb);
        async_cp16(vp + vOff0, Vs + wb);
        async_cp16(vp + vOff1, Vs + 2048 + wb);
    };

    floatx16 accO[2] = {};
    float mr = NEGINF, lr = 0.f;

    stage(0); stage(1); stage(2);

    for (int kt = 0; kt < n; ++kt) {
        asm volatile("s_waitcnt vmcnt(8)" ::: "memory");  // oldest stage landed
        asm volatile("s_barrier" ::: "memory");
        {
            int jn = kt + 3;
            stage(jn < n ? jn : n - 1);  // uniform 4 loads/iter
        }
        if (kt < my_n) {
            const u16* Ks = (const u16*)KV[kt & 3][0];
            const u16* Vs = (const u16*)KV[kt & 3][1];

            // S^T[key][q] = K Q^T, two 32-key halves, 4 K=16 chunks over d
            floatx16 sa[2];
            sa[0] = 0.f; sa[1] = 0.f;
#pragma unroll
            for (int kh = 0; kh < 2; ++kh) {
                int row = kh * 32 + l31;
                int swr = row & 7;
#pragma unroll
                for (int ck = 0; ck < 4; ++ck) {
                    int cc = (ck * 2 + h5) ^ swr;
                    short8 kf = *(const short8*)&Ks[row * 64 + cc * 8];
                    sa[kh] = MFMA32(kf, qf[ck], sa[kh]);
                }
            }
            if (kt == myqt) {  // diagonal: causal mask (wave-uniform branch)
#pragma unroll
                for (int kh = 0; kh < 2; ++kh)
#pragma unroll
                    for (int rg = 0; rg < 16; ++rg) {
                        int key = kt * 64 + kh * 32 + (rg & 3) + 8 * (rg >> 2) + 4 * h5;
                        if (key > q_abs) sa[kh][rg] = NEGINF;
                    }
            }
            // online softmax: q = lane&31 fixed per lane; partner = lane^32
            float mx = NEGINF;
#pragma unroll
            for (int kh = 0; kh < 2; ++kh)
#pragma unroll
                for (int rg = 0; rg < 16; ++rg) mx = fmaxf(mx, sa[kh][rg]);
            mx = fmaxf(mx, __shfl_xor(mx, 32));
            float m_new = fmaxf(mr, mx);
            if (__ballot(m_new > mr)) {  // rarely true after early tiles
                float alpha = EXP2(mr - m_new);
                lr *= alpha;
                accO[0] *= alpha;
                accO[1] *= alpha;
            }
            mr = m_new;
            float p[2][16];
            float rs = 0.f;
#pragma unroll
            for (int kh = 0; kh < 2; ++kh)
#pragma unroll
                for (int rg = 0; rg < 16; ++rg) {
                    float e = EXP2(sa[kh][rg] - m_new);
                    p[kh][rg] = e;
                    rs += e;
                }
            rs += __shfl_xor(rs, 32);
            lr += rs;
            // pack P pairs: pk[kh][g] = (p[2g], p[2g+1]) -> rid 2*(g&1)+8*(g>>1)+4*h5 +{0,1}
            uint32_t pk[2][8];
#pragma unroll
            for (int kh = 0; kh < 2; ++kh)
#pragma unroll
                for (int g = 0; g < 8; ++g)
                    pk[kh][g] = pkbf(p[kh][2 * g], p[kh][2 * g + 1]);
            // PV: for each 16-key block, assemble B-frag (keys h5*8+j) via
            // cross-half exchange, then accumulate both d-halves.
#pragma unroll
            for (int kb = 0; kb < 4; ++kb) {
                int hh = kb >> 1;
                int base = 4 * (kb & 1);
                uint32_t o0 = pk[hh][base + 2 * h5];
                uint32_t o1 = pk[hh][base + 2 * h5 + 1];
                uint32_t s0 = pk[hh][base + 2 * (1 - h5)];
                uint32_t s1 = pk[hh][base + 2 * (1 - h5) + 1];
                uint32_t e0 = (uint32_t)__shfl_xor((int)s0, 32);
                uint32_t e1 = (uint32_t)__shfl_xor((int)s1, 32);
                union { uint32_t u[4]; short8 v; } pf;
                pf.u[0] = h5 ? e0 : o0;
                pf.u[1] = h5 ? e1 : o1;
                pf.u[2] = h5 ? o0 : e0;
                pf.u[3] = h5 ? o1 : e1;
#pragma unroll
                for (int dh = 0; dh < 2; ++dh) {
                    int vrow = dh * 32 + l31;
                    int cc = (kb * 2 + h5) ^ (vrow & 7);
                    short8 vf = *(const short8*)&Vs[vrow * 64 + cc * 8];
                    accO[dh] = MFMA32(vf, pf.v, accO[dh]);
                }
            }
        }
    }

    // epilogue: O[q=lane&31][d = dh*32 + rid], inv lane-local, paired stores
    float inv = 1.f / lr;
    size_t obase = ((size_t)(b * 2048 + q_abs)) * 1024 + h * 64;
#pragma unroll
    for (int dh = 0; dh < 2; ++dh)
#pragma unroll
        for (int g = 0; g < 8; ++g) {
            int d0 = dh * 32 + 2 * (g & 1) + 8 * (g >> 1) + 4 * h5;
            uint32_t v = pkbf(accO[dh][2 * g] * inv, accO[dh][2 * g + 1] * inv);
            *(uint32_t*)&attnb[obase + d0] = v;
        }
}

// ---------------- launch ----------------

extern "C" void kernel_launch(void* const* d_in, const int* in_sizes, int n_in,
                              void* d_out, int out_size, void* d_ws, size_t ws_size,
                              hipStream_t stream) {
    const float* x     = (const float*)d_in[0];
    const float* W_qkv = (const float*)d_in[1];
    const float* b_qkv = (const float*)d_in[2];
    const float* W_out = (const float*)d_in[3];
    const float* b_out = (const float*)d_in[4];
    float* out = (float*)d_out;

    char* p = (char*)d_ws;
    u16* xb    = (u16*)p; p += (size_t)4096 * 1024 * 2;     // 8 MB (reused as attn out)
    u16* wqkvT = (u16*)p; p += (size_t)3072 * 1024 * 2;     // 6 MB
    u16* woutT = (u16*)p; p += (size_t)1024 * 1024 * 2;     // 2 MB
    u16* Qb    = (u16*)p; p += (size_t)32 * 2048 * 64 * 2;  // 8 MB (pre-scaled, exp2 domain)
    u16* Kb    = (u16*)p; p += (size_t)32 * 2048 * 64 * 2;  // 8 MB
    u16* Vtb   = (u16*)p; p += (size_t)32 * 64 * 2048 * 2;  // 8 MB [bh][d][s]
    u16* attnb = xb;  // xb dead after k_qkv_gemm

    k_prep<<<6144, 256, 0, stream>>>(x, W_qkv, W_out, xb, wqkvT, woutT);
    k_qkv_gemm<<<dim3(24, 32), 256, 0, stream>>>(xb, wqkvT, b_qkv, Qb, Kb, Vtb);
    k_attn<<<512, 256, 0, stream>>>(Qb, Kb, Vtb, attnb);
    k_out_gemm<<<dim3(8, 64), 256, 0, stream>>>(attnb, woutT, b_out, out);
}

// Round 8
// 177.283 us; speedup vs baseline: 1.2816x; 1.2816x over previous
//
#include <hip/hip_runtime.h>
#include <hip/hip_bf16.h>
#include <cstdint>
#include <cstddef>

// ---------------------------------------------------------------------------
// MultiHeadAttention  B=2 S=2048 E=1024 H=16 D=64 causal, bf16 MFMA path.
// k_prep -> qkv gemm (ring-3 BK=32) -> flash attn (128-row q-block, two
// 64-row strips sharing one K/V stream; 16x16 MFMA path from R6; ring-4 LDS,
// raw s_barrier + vmcnt(8)) -> out gemm (ring-3 BK=32).
// ---------------------------------------------------------------------------

typedef unsigned short u16;
typedef __attribute__((ext_vector_type(8))) short short8;
typedef __attribute__((ext_vector_type(4))) short short4v;
typedef __attribute__((ext_vector_type(4))) float floatx4;

#define MFMA16(a, b, c) __builtin_amdgcn_mfma_f32_16x16x32_bf16((a), (b), (c), 0, 0, 0)

#if __has_builtin(__builtin_amdgcn_mfma_f32_16x16x16_bf16)
#define PV_MFMA(a, b, c) __builtin_amdgcn_mfma_f32_16x16x16_bf16((a), (b), (c), 0, 0, 0)
#elif __has_builtin(__builtin_amdgcn_mfma_f32_16x16x16bf16_1k)
#define PV_MFMA(a, b, c) __builtin_amdgcn_mfma_f32_16x16x16bf16_1k((a), (b), (c), 0, 0, 0)
#else
static __device__ __forceinline__ floatx4 pv_mfma_asm(short4v a, short4v b, floatx4 c) {
    asm volatile("v_mfma_f32_16x16x16_bf16 %0, %1, %2, %0" : "+v"(c) : "v"(a), "v"(b));
    return c;
}
#define PV_MFMA(a, b, c) pv_mfma_asm((a), (b), (c))
#endif

#if __has_builtin(__builtin_amdgcn_exp2f)
#define EXP2(x) __builtin_amdgcn_exp2f(x)
#else
#define EXP2(x) exp2f(x)
#endif

#define QSCALE 0.18033688011f  // 0.125 * log2(e)
#define NEGINF (-__builtin_inff())

static __device__ __forceinline__ u16 f2b(float f) {
    union { float f; uint32_t u; } v; v.f = f;
    return (u16)((v.u + 0x7fffu + ((v.u >> 16) & 1u)) >> 16);  // RNE
}

static __device__ __forceinline__ uint32_t pkbf(float lo, float hi) {
    union { float f; uint32_t u; } a, b; a.f = lo; b.f = hi;
    return __builtin_amdgcn_perm(b.u + 0x8000u, a.u + 0x8000u, 0x07060302u);
}

static __device__ __forceinline__ void async_cp16(const u16* g, u16* lds_wave_base) {
    __builtin_amdgcn_global_load_lds((__attribute__((address_space(1))) void*)g,
                                     (__attribute__((address_space(3))) void*)lds_wave_base,
                                     16, 0, 0);
}

// ---------------- fused prep: x->bf16, W_qkv^T->bf16, W_out^T->bf16 ---------

__global__ __launch_bounds__(256) void k_prep(const float* __restrict__ x,
                                              const float* __restrict__ Wq,
                                              const float* __restrict__ Wo,
                                              u16* __restrict__ xb,
                                              u16* __restrict__ wqkvT,
                                              u16* __restrict__ woutT) {
    int bx = blockIdx.x, tid = threadIdx.x;
    if (bx < 2048) {
        int g = bx * 256 + tid;
        const float4* s = (const float4*)x + (size_t)g * 2;
        float4 f0 = s[0], f1 = s[1];
        uint4 r;
        r.x = pkbf(f0.x, f0.y);
        r.y = pkbf(f0.z, f0.w);
        r.z = pkbf(f1.x, f1.y);
        r.w = pkbf(f1.z, f1.w);
        *(uint4*)(xb + (size_t)g * 8) = r;
        return;
    }
    __shared__ float t[32][33];
    const float* src;
    u16* dst;
    int R, C, b;
    if (bx < 5120) { b = bx - 2048; src = Wq; dst = wqkvT; R = 1024; C = 3072; }
    else           { b = bx - 5120; src = Wo; dst = woutT; R = 1024; C = 1024; }
    int nbx = C >> 5;
    int yq = b / nbx, xq = b - yq * nbx;
    int c0 = xq * 32, r0 = yq * 32;
    int tx = tid & 31, ty = tid >> 5;
#pragma unroll
    for (int i = 0; i < 4; ++i)
        t[ty + i * 8][tx] = src[(size_t)(r0 + ty + i * 8) * C + c0 + tx];
    __syncthreads();
#pragma unroll
    for (int i = 0; i < 4; ++i)
        dst[(size_t)(c0 + ty + i * 8) * R + r0 + tx] = f2b(t[tx][ty + i * 8]);
}

// ---------------- qkv GEMM: 128x128, BK=32, ring-3 pipeline -----------------

__global__ __launch_bounds__(256, 3) void k_qkv_gemm(const u16* __restrict__ A,
                                                     const u16* __restrict__ Bt,
                                                     const float* __restrict__ bias,
                                                     u16* __restrict__ Qb,
                                                     u16* __restrict__ Kb,
                                                     u16* __restrict__ Vtb) {
    __shared__ __align__(16) u16 As[3][128 * 32];
    __shared__ __align__(16) u16 Bs[3][128 * 32];
    int tid = threadIdx.x;
    int w = tid >> 6, lane = tid & 63, quad = lane >> 4, l16 = lane & 15;
    int wm = w >> 1, wn = w & 1;
    int m0 = blockIdx.y * 128, n0 = blockIdx.x * 128;
    int wb = (tid & ~63) * 8;

    int ra0 = tid >> 2, ca0 = (tid & 3) * 8;
    int ra1 = (256 + tid) >> 2, ca1 = (tid & 3) * 8;
    const u16* A0 = &A[(size_t)(m0 + ra0) * 1024 + ca0];
    const u16* A1 = &A[(size_t)(m0 + ra1) * 1024 + ca1];
    const u16* B0 = &Bt[(size_t)(n0 + ra0) * 1024 + ca0];
    const u16* B1 = &Bt[(size_t)(n0 + ra1) * 1024 + ca1];

    auto stage = [&](int src_kt, int slot) {
        int ko = src_kt * 32;
        async_cp16(A0 + ko, &As[slot][wb]);
        async_cp16(A1 + ko, &As[slot][2048 + wb]);
        async_cp16(B0 + ko, &Bs[slot][wb]);
        async_cp16(B1 + ko, &Bs[slot][2048 + wb]);
    };

    floatx4 acc[4][4] = {};
    stage(0, 0);
    stage(1, 1);

    for (int kt = 0; kt < 32; ++kt) {
        asm volatile("s_waitcnt vmcnt(4)" ::: "memory");
        asm volatile("s_barrier" ::: "memory");
        int jn = kt + 2;
        stage(jn < 32 ? jn : 31, jn % 3);
        int s = kt % 3;
        short8 af[4], bf[4];
#pragma unroll
        for (int mt = 0; mt < 4; ++mt)
            af[mt] = *(const short8*)&As[s][(wm * 64 + mt * 16 + l16) * 32 + quad * 8];
#pragma unroll
        for (int nt = 0; nt < 4; ++nt)
            bf[nt] = *(const short8*)&Bs[s][(wn * 64 + nt * 16 + l16) * 32 + quad * 8];
#pragma unroll
        for (int mt = 0; mt < 4; ++mt)
#pragma unroll
            for (int nt = 0; nt < 4; ++nt)
                acc[mt][nt] = MFMA16(af[mt], bf[nt], acc[mt][nt]);
    }

    int region = n0 >> 10;  // 0=Q 1=K 2=V
    if (region == 2) {
#pragma unroll
        for (int mt = 0; mt < 4; ++mt)
#pragma unroll
            for (int nt = 0; nt < 4; ++nt) {
                int n_abs = n0 + wn * 64 + nt * 16 + l16;
                int e = n_abs & 1023, h = e >> 6, d = e & 63;
                float vb = bias[n_abs];
                int mrow = m0 + wm * 64 + mt * 16 + quad * 4;
                int b = mrow >> 11, s0 = mrow & 2047;
                uint2 val;
                val.x = pkbf(acc[mt][nt][0] + vb, acc[mt][nt][1] + vb);
                val.y = pkbf(acc[mt][nt][2] + vb, acc[mt][nt][3] + vb);
                *(uint2*)&Vtb[((size_t)(b * 16 + h) * 64 + d) * 2048 + s0] = val;
            }
    } else {
        u16* dst = region == 0 ? Qb : Kb;
        float scl = region == 0 ? QSCALE : 1.0f;
#pragma unroll
        for (int mt = 0; mt < 4; ++mt)
#pragma unroll
            for (int nt = 0; nt < 4; ++nt)
#pragma unroll
                for (int r = 0; r < 4; ++r) {
                    int m_abs = m0 + wm * 64 + mt * 16 + quad * 4 + r;
                    int n_abs = n0 + wn * 64 + nt * 16 + l16;
                    float val = (acc[mt][nt][r] + bias[n_abs]) * scl;
                    int e = n_abs & 1023, h = e >> 6, d = e & 63;
                    int b = m_abs >> 11, s = m_abs & 2047;
                    dst[((size_t)(b * 16 + h) * 2048 + s) * 64 + d] = f2b(val);
                }
    }
}

// ---------------- out GEMM: 64x128, BK=32, ring-3 pipeline ------------------

__global__ __launch_bounds__(256, 4) void k_out_gemm(const u16* __restrict__ A,
                                                     const u16* __restrict__ Bt,
                                                     const float* __restrict__ bias,
                                                     float* __restrict__ out) {
    __shared__ __align__(16) u16 As[3][64 * 32];
    __shared__ __align__(16) u16 Bs[3][128 * 32];
    int tid = threadIdx.x;
    int w = tid >> 6, lane = tid & 63, quad = lane >> 4, l16 = lane & 15;
    int wm = w >> 1, wn = w & 1;
    int m0 = blockIdx.y * 64, n0 = blockIdx.x * 128;
    int wb = (tid & ~63) * 8;

    int ra0 = tid >> 2, ca0 = (tid & 3) * 8;
    int ra1 = (256 + tid) >> 2;
    const u16* A0 = &A[(size_t)(m0 + ra0) * 1024 + ca0];
    const u16* B0 = &Bt[(size_t)(n0 + ra0) * 1024 + ca0];
    const u16* B1 = &Bt[(size_t)(n0 + ra1) * 1024 + ca0];

    auto stage = [&](int src_kt, int slot) {
        int ko = src_kt * 32;
        async_cp16(A0 + ko, &As[slot][wb]);
        async_cp16(B0 + ko, &Bs[slot][wb]);
        async_cp16(B1 + ko, &Bs[slot][2048 + wb]);
    };

    floatx4 acc[2][4] = {};
    stage(0, 0);
    stage(1, 1);

    for (int kt = 0; kt < 32; ++kt) {
        asm volatile("s_waitcnt vmcnt(3)" ::: "memory");
        asm volatile("s_barrier" ::: "memory");
        int jn = kt + 2;
        stage(jn < 32 ? jn : 31, jn % 3);
        int s = kt % 3;
        short8 af[2], bf[4];
#pragma unroll
        for (int mt = 0; mt < 2; ++mt)
            af[mt] = *(const short8*)&As[s][(wm * 32 + mt * 16 + l16) * 32 + quad * 8];
#pragma unroll
        for (int nt = 0; nt < 4; ++nt)
            bf[nt] = *(const short8*)&Bs[s][(wn * 64 + nt * 16 + l16) * 32 + quad * 8];
#pragma unroll
        for (int mt = 0; mt < 2; ++mt)
#pragma unroll
            for (int nt = 0; nt < 4; ++nt)
                acc[mt][nt] = MFMA16(af[mt], bf[nt], acc[mt][nt]);
    }

#pragma unroll
    for (int mt = 0; mt < 2; ++mt)
#pragma unroll
        for (int nt = 0; nt < 4; ++nt)
#pragma unroll
            for (int r = 0; r < 4; ++r) {
                int m_abs = m0 + wm * 32 + mt * 16 + quad * 4 + r;
                int n_abs = n0 + wn * 64 + nt * 16 + l16;
                out[(size_t)m_abs * 1024 + n_abs] = acc[mt][nt][r] + bias[n_abs];
            }
}

// ---------------- flash attention: 128-row q-block, two strips --------------
// grid 512: bh = (L&7)*4 + (L>>3)&3 (4 heads/XCD, K/V L2-resident);
// tile = idx<8 ? idx : 23-idx  (co-resident pair L, L+256 sums to 34 iters).
// Block covers q-rows [tile*128, tile*128+128): strip0 = first 64 (4 waves x
// 16 rows), strip1 = last 64. One K/V stream kt=0..2*tile+1; per iter the
// K/V fragments are read from LDS ONCE and drive both strips' tile_steps
// (strip0 skips only the final iter). 16x16 MFMA path identical to R6
// (S^T trick, lane-local softmax, swapped-operand PV). Ring-4 + vmcnt(8).

__global__ __launch_bounds__(256, 2) void k_attn(const u16* __restrict__ Qb,
                                                 const u16* __restrict__ Kb,
                                                 const u16* __restrict__ Vtb,
                                                 u16* __restrict__ attnb) {
    __shared__ __align__(16) u16 KV[4][2][4096];  // [slot][K/V][64x64]
    int tid = threadIdx.x;
    int w = tid >> 6, lane = tid & 63, quad = lane >> 4, l16 = lane & 15;
    int L = blockIdx.x;
    int bh = ((L & 7) << 2) | ((L >> 3) & 3);
    int idx = (L >> 5) & 15;
    int tile = idx < 8 ? idx : 23 - idx;
    const u16* Qp = Qb + (size_t)bh * 131072;
    const u16* Kp = Kb + (size_t)bh * 131072;
    const u16* Vp = Vtb + (size_t)bh * 131072;
    int b = bh >> 4, h = bh & 15;

    // staging offsets (XOR-swizzled chunk layout, wave-uniform LDS base)
    int r0 = tid >> 3, c0 = ((tid & 7) ^ (r0 & 7)) * 8;
    int f1 = 256 + tid;
    int r1 = f1 >> 3, c1 = ((f1 & 7) ^ (r1 & 7)) * 8;
    int kOff0 = r0 * 64 + c0, kOff1 = r1 * 64 + c1;
    int vOff0 = r0 * 2048 + c0, vOff1 = r1 * 2048 + c1;
    int wb = (tid & ~63) * 8;

    // Q fragments for both strips
    int q_s0 = tile * 128 + w * 16 + l16;
    int q_s1 = q_s0 + 64;
    short8 q00 = *(const short8*)&Qp[(size_t)q_s0 * 64 + quad * 8];
    short8 q01 = *(const short8*)&Qp[(size_t)q_s0 * 64 + 32 + quad * 8];
    short8 q10 = *(const short8*)&Qp[(size_t)q_s1 * 64 + quad * 8];
    short8 q11 = *(const short8*)&Qp[(size_t)q_s1 * 64 + 32 + quad * 8];

    int n = 2 * tile + 2;  // K-tiles to stream

    auto stage = [&](int j) {
        u16* Ks = (u16*)KV[j & 3][0];
        u16* Vs = (u16*)KV[j & 3][1];
        const u16* kp = Kp + (size_t)j * 4096;
        const u16* vp = Vp + (size_t)j * 64;
        async_cp16(kp + kOff0, Ks + wb);
        async_cp16(kp + kOff1, Ks + 2048 + wb);
        async_cp16(vp + vOff0, Vs + wb);
        async_cp16(vp + vOff1, Vs + 2048 + wb);
    };

    floatx4 acc0[4] = {}, acc1[4] = {};
    float m0 = NEGINF, l0 = 0.f;
    float m1 = NEGINF, l1 = 0.f;
    int sw = l16 & 7;

    stage(0); stage(1); stage(2);

    for (int kt = 0; kt < n; ++kt) {
        asm volatile("s_waitcnt vmcnt(8)" ::: "memory");  // oldest stage landed
        asm volatile("s_barrier" ::: "memory");
        {
            int jn = kt + 3;
            stage(jn < n ? jn : n - 1);  // uniform 4 loads/iter
        }
        const u16* Ks = (const u16*)KV[kt & 3][0];
        const u16* Vs = (const u16*)KV[kt & 3][1];

        // shared fragments: K (B-frag of QK^T) and V^T (A-frag of PV)
        short8 kfa[4], kfb[4];
#pragma unroll
        for (int nt = 0; nt < 4; ++nt) {
            int rb = (nt * 16 + l16) * 8;
            kfa[nt] = *(const short8*)&Ks[(rb + (quad ^ sw)) * 8];
            kfb[nt] = *(const short8*)&Ks[(rb + ((4 + quad) ^ sw)) * 8];
        }
        short4v vf[4][4];
#pragma unroll
        for (int dt = 0; dt < 4; ++dt) {
            const char* rowb = (const char*)Vs + (dt * 16 + l16) * 128 + (quad & 1) * 8;
#pragma unroll
            for (int nt = 0; nt < 4; ++nt) {
                int chunk = nt * 2 + (quad >> 1);
                vf[nt][dt] = *(const short4v*)(rowb + ((chunk ^ sw) * 16));
            }
        }

        auto tile_step = [&](short8 qf0, short8 qf1, int q_abs, bool diag, float& mr,
                             float& lr, floatx4* accO) {
            // S^T: lane holds S[q-row = l16 of wave][key = kt*64+nt*16+quad*4+r]
            floatx4 sa[4] = {};
#pragma unroll
            for (int nt = 0; nt < 4; ++nt) {
                sa[nt] = MFMA16(kfa[nt], qf0, sa[nt]);
                sa[nt] = MFMA16(kfb[nt], qf1, sa[nt]);
            }
            if (diag) {  // causal mask (block-uniform branch)
#pragma unroll
                for (int nt = 0; nt < 4; ++nt)
#pragma unroll
                    for (int r = 0; r < 4; ++r)
                        if (kt * 64 + nt * 16 + quad * 4 + r > q_abs)
                            sa[nt][r] = NEGINF;
            }
            float v = sa[0][0];
#pragma unroll
            for (int nt = 0; nt < 4; ++nt)
#pragma unroll
                for (int r = 0; r < 4; ++r) v = fmaxf(v, sa[nt][r]);
            v = fmaxf(v, __shfl_xor(v, 16));
            v = fmaxf(v, __shfl_xor(v, 32));
            float m_new = fmaxf(mr, v);
            float alpha = EXP2(mr - m_new);
            float p[4][4];
            float rs = 0.f;
#pragma unroll
            for (int nt = 0; nt < 4; ++nt)
#pragma unroll
                for (int r = 0; r < 4; ++r) {
                    float e = EXP2(sa[nt][r] - m_new);
                    p[nt][r] = e;
                    rs += e;
                }
            rs += __shfl_xor(rs, 16);
            rs += __shfl_xor(rs, 32);
            lr = lr * alpha + rs;
            mr = m_new;
#pragma unroll
            for (int dt = 0; dt < 4; ++dt)
#pragma unroll
                for (int r = 0; r < 4; ++r) accO[dt][r] *= alpha;  // lane-local
#pragma unroll
            for (int nt = 0; nt < 4; ++nt) {
                union { uint2 u; short4v s; } pf;
                pf.u.x = pkbf(p[nt][0], p[nt][1]);
                pf.u.y = pkbf(p[nt][2], p[nt][3]);
#pragma unroll
                for (int dt = 0; dt < 4; ++dt)
                    accO[dt] = PV_MFMA(vf[nt][dt], pf.s, accO[dt]);
            }
        };

        tile_step(q10, q11, q_s1, kt == n - 1, m1, l1, acc1);        // strip1: all iters
        if (kt < n - 1)
            tile_step(q00, q01, q_s0, kt == n - 2, m0, l0, acc0);    // strip0: skip last
    }

    // epilogue: O[q=l16-row][d=dt*16+quad*4+r], inv lane-local -> 8B stores
    auto epilogue = [&](int q_abs, float lr, const floatx4* accO) {
        float inv = 1.f / lr;
        size_t base = ((size_t)(b * 2048 + q_abs)) * 1024 + h * 64;
#pragma unroll
        for (int dt = 0; dt < 4; ++dt) {
            uint2 val;
            val.x = pkbf(accO[dt][0] * inv, accO[dt][1] * inv);
            val.y = pkbf(accO[dt][2] * inv, accO[dt][3] * inv);
            *(uint2*)&attnb[base + dt * 16 + quad * 4] = val;
        }
    };
    epilogue(q_s0, l0, acc0);
    epilogue(q_s1, l1, acc1);
}

// ---------------- launch ----------------

extern "C" void kernel_launch(void* const* d_in, const int* in_sizes, int n_in,
                              void* d_out, int out_size, void* d_ws, size_t ws_size,
                              hipStream_t stream) {
    const float* x     = (const float*)d_in[0];
    const float* W_qkv = (const float*)d_in[1];
    const float* b_qkv = (const float*)d_in[2];
    const float* W_out = (const float*)d_in[3];
    const float* b_out = (const float*)d_in[4];
    float* out = (float*)d_out;

    char* p = (char*)d_ws;
    u16* xb    = (u16*)p; p += (size_t)4096 * 1024 * 2;     // 8 MB (reused as attn out)
    u16* wqkvT = (u16*)p; p += (size_t)3072 * 1024 * 2;     // 6 MB
    u16* woutT = (u16*)p; p += (size_t)1024 * 1024 * 2;     // 2 MB
    u16* Qb    = (u16*)p; p += (size_t)32 * 2048 * 64 * 2;  // 8 MB (pre-scaled, exp2 domain)
    u16* Kb    = (u16*)p; p += (size_t)32 * 2048 * 64 * 2;  // 8 MB
    u16* Vtb   = (u16*)p; p += (size_t)32 * 64 * 2048 * 2;  // 8 MB [bh][d][s]
    u16* attnb = xb;  // xb dead after k_qkv_gemm

    k_prep<<<6144, 256, 0, stream>>>(x, W_qkv, W_out, xb, wqkvT, woutT);
    k_qkv_gemm<<<dim3(24, 32), 256, 0, stream>>>(xb, wqkvT, b_qkv, Qb, Kb, Vtb);
    k_attn<<<512, 256, 0, stream>>>(Qb, Kb, Vtb, attnb);
    k_out_gemm<<<dim3(8, 64), 256, 0, stream>>>(attnb, woutT, b_out, out);
}